// Round 8
// baseline (381.967 us; speedup 1.0000x reference)
//
#include <hip/hip_runtime.h>
#include <hip/hip_bf16.h>
#include <math.h>

typedef __attribute__((ext_vector_type(8))) short short8;
typedef __attribute__((ext_vector_type(16))) float f32x16;

namespace {
// ---- LDS arena BYTE layout ----
constexpr int XB0 = 0;            // x bf16 [60][62]
constexpr int EBF0 = 7440;        // ebar f32 [60][20]
constexpr int EBB0 = 12240;       // ebar bf16 [60][20]
constexpr int YB0 = 14640;        // y bf16 [5][14]
constexpr int ZS = 14780;         // zero u16
constexpr int ARENA_B = 14784;

// ---- ws byte offsets ----
constexpr int NTAB_PP = 111 * 8 * 64 * 8;   // u16 entries
constexpr int NTAB_PV = 27 * 5 * 64 * 8;
constexpr int NTAB_O  = 2 * 5 * 64 * 8;
constexpr int TABPP_B = 0;
constexpr int TABPV_B = TABPP_B + NTAB_PP * 2;   // 909312
constexpr int TABO_B  = TABPV_B + NTAB_PV * 2;   // 1047552
constexpr int WPP1_B  = TABO_B + NTAB_O * 2;     // 1057792, 16 frags (1KB each)
constexpr int WPP2_B  = WPP1_B + 16 * 1024;      // 4 frags
constexpr int WPV1_B  = WPP2_B + 4 * 1024;       // 10 frags
constexpr int WPV2_B  = WPV1_B + 10 * 1024;      // 4 frags
constexpr int WO1_B   = WPV2_B + 4 * 1024;       // 10 frags
constexpr int WO2_B   = WO1_B + 10 * 1024;       // 4 frags
constexpr int BIAS_B  = WO2_B + 4 * 1024;        // 288 f32
}

__device__ __forceinline__ short f2bfs(float f) {
  __hip_bfloat16 h = __float2bfloat16(f);
  short s;
  __builtin_memcpy(&s, &h, 2);
  return s;
}

__device__ __forceinline__ f32x16 splat16(float v) {
  f32x16 s;
#pragma unroll
  for (int i = 0; i < 16; ++i) s[i] = v;
  return s;
}

// ---------------- init: gather tables (u16 BYTE offsets into bf16 arena) ----------------
__global__ __launch_bounds__(256) void build_tables(char* wsb) {
  int t = blockIdx.x * 256 + threadIdx.x;
  unsigned short* tpp = (unsigned short*)(wsb + TABPP_B);
  unsigned short* tpv = (unsigned short*)(wsb + TABPV_B);
  unsigned short* tou = (unsigned short*)(wsb + TABO_B);
  if (t < NTAB_PP) {
    int j = t & 7, l = (t >> 3) & 63, blk = t >> 9;
    int ks = blk & 7, mt = blk >> 3;
    int rr = mt * 32 + (l & 31), k = ks * 16 + ((l >> 5) * 8) + j;
    unsigned off = ZS;
    if (rr < 3540 && k < 120) {
      unsigned p = (unsigned)rr * 120u + (unsigned)k;
      unsigned f = p / 3540u, e = p - f * 3540u;
      unsigned i = e / 59u, jj = e - i * 59u;
      unsigned col = (f < 60u) ? i : ((jj < i) ? jj : jj + 1u);
      unsigned ft = (f < 60u) ? f : f - 60u;
      off = XB0 + (ft * 62u + col) * 2u;
    }
    tpp[t] = (unsigned short)off;
    return;
  }
  t -= NTAB_PP;
  if (t < NTAB_PV) {
    int j = t & 7, l = (t >> 3) & 63, blk = t >> 9;
    int ks = blk % 5, mt = blk / 5;
    int tt = mt * 32 + (l & 31), k = ks * 16 + ((l >> 5) * 8) + j;
    unsigned off = ZS;
    if (tt < 840 && k < 65) {
      int i = tt / 14, v = tt - i * 14;
      off = (k < 60) ? (unsigned)(XB0 + (k * 62 + i) * 2)
                     : (unsigned)(YB0 + ((k - 60) * 14 + v) * 2);
    }
    tpv[t] = (unsigned short)off;
    return;
  }
  t -= NTAB_PV;
  if (t < NTAB_O) {
    int j = t & 7, l = (t >> 3) & 63, blk = t >> 9;
    int ks = blk % 5, mt = blk / 5;
    int r = mt * 32 + (l & 31), k = ks * 16 + ((l >> 5) * 8) + j;
    unsigned off = ZS;
    if (r < 60 && k < 80)
      off = (k < 60) ? (unsigned)(XB0 + (r * 62 + k) * 2)
                     : (unsigned)(EBB0 + (r * 20 + (k - 60)) * 2);
    tou[t] = (unsigned short)off;
  }
}

// ---------------- init: weight fragments (bf16, 32x32x16 B-layout) + biases ----------------
// B-frag: lane l holds B[k = ks*16 + (l>>5)*8 + 2d(+1)][n = nt*32 + (l&31)]
__global__ __launch_bounds__(256) void build_wfrag(char* wsb,
    const float* W1pp, const float* W2pp, const float* W1pv, const float* W2pv,
    const float* W1o, const float* W2o,
    const float* b1pp, const float* b2pp, const float* b1pv, const float* b2pv,
    const float* b1o, const float* b2o) {
  int t = blockIdx.x * 256 + threadIdx.x;
  if (t < 12288) {
    const float* W; int Kt, Nt, NT; unsigned* dst; int local;
    if (t < 4096)        { W = W1pp; Kt = 120; Nt = 60; NT = 2; dst = (unsigned*)(wsb + WPP1_B); local = t; }
    else if (t < 5120)   { W = W2pp; Kt = 60;  Nt = 20; NT = 1; dst = (unsigned*)(wsb + WPP2_B); local = t - 4096; }
    else if (t < 7680)   { W = W1pv; Kt = 65;  Nt = 60; NT = 2; dst = (unsigned*)(wsb + WPV1_B); local = t - 5120; }
    else if (t < 8704)   { W = W2pv; Kt = 60;  Nt = 20; NT = 1; dst = (unsigned*)(wsb + WPV2_B); local = t - 7680; }
    else if (t < 11264)  { W = W1o;  Kt = 80;  Nt = 60; NT = 2; dst = (unsigned*)(wsb + WO1_B);  local = t - 8704; }
    else                 { W = W2o;  Kt = 60;  Nt = 24; NT = 1; dst = (unsigned*)(wsb + WO2_B);  local = t - 11264; }
    int d = local & 3, l = (local >> 2) & 63, fi = local >> 8;
    int nt = fi % NT, ks = fi / NT;
    int k = ks * 16 + (l >> 5) * 8 + 2 * d, n = nt * 32 + (l & 31);
    float v0 = (k < Kt && n < Nt) ? W[k * Nt + n] : 0.f;
    float v1 = (k + 1 < Kt && n < Nt) ? W[(k + 1) * Nt + n] : 0.f;
    unsigned u0 = (unsigned short)f2bfs(v0);
    unsigned u1 = (unsigned short)f2bfs(v1);
    dst[local] = u0 | (u1 << 16);
    return;
  }
  t -= 12288;
  if (t < 288) {
    float* bd = (float*)(wsb + BIAS_B);
    float v = 0.f;
    if (t < 64)       { if (t < 60) v = b1pp[t]; }
    else if (t < 96)  { int n = t - 64;  if (n < 20) v = b2pp[n]; }
    else if (t < 160) { int n = t - 96;  if (n < 60) v = b1pv[n]; }
    else if (t < 192) { int n = t - 160; if (n < 20) v = b2pv[n]; }
    else if (t < 256) { int n = t - 192; if (n < 60) v = b1o[n]; }
    else              { int n = t - 256; if (n < 24) v = b2o[n]; }
    bd[t] = v;
  }
}

// ---- one 32-row M-tile: gathered-A 32x32x16 stage1 -> relu -> H LDS -> stage2 ----
// A-frag: lane holds A[m=l&31][k=ks*16+(l>>5)*8+j]; C/D: col=l&31, row=(reg&3)+8*(reg>>2)+4*(l>>5).
template <int NKS>
__device__ __forceinline__ void mlp32(
    int mt, int lane, const uint4* __restrict__ tab,
    const short8* wf1, const short8* wf2,     // LDS
    float b1a, float b1b, float b2,
    const unsigned char* arena_b, short (*hrow)[72], f32x16& eo)
{
  const int cl = lane & 31, hi = lane >> 5;

  f32x16 acc0 = splat16(b1a);
  f32x16 acc1 = splat16(b1b);

#pragma unroll
  for (int ks = 0; ks < NKS; ++ks) {
    uint4 tw = tab[(mt * NKS + ks) * 64 + lane];
    short8 af;
    af[0] = *(const short*)(arena_b + (tw.x & 0xffffu));
    af[1] = *(const short*)(arena_b + (tw.x >> 16));
    af[2] = *(const short*)(arena_b + (tw.y & 0xffffu));
    af[3] = *(const short*)(arena_b + (tw.y >> 16));
    af[4] = *(const short*)(arena_b + (tw.z & 0xffffu));
    af[5] = *(const short*)(arena_b + (tw.z >> 16));
    af[6] = *(const short*)(arena_b + (tw.w & 0xffffu));
    af[7] = *(const short*)(arena_b + (tw.w >> 16));
    short8 w0 = wf1[(ks * 2 + 0) * 64 + lane];
    short8 w1 = wf1[(ks * 2 + 1) * 64 + lane];
    acc0 = __builtin_amdgcn_mfma_f32_32x32x16_bf16(af, w0, acc0, 0, 0, 0);
    acc1 = __builtin_amdgcn_mfma_f32_32x32x16_bf16(af, w1, acc1, 0, 0, 0);
  }

  // relu -> per-wave H tile [32][72 pad] bf16
#pragma unroll
  for (int g = 0; g < 4; ++g)
#pragma unroll
    for (int q = 0; q < 4; ++q) {
      int row = q + 8 * g + 4 * hi;
      int reg = g * 4 + q;
      hrow[row][cl] = f2bfs(fmaxf(acc0[reg], 0.f));
      hrow[row][32 + cl] = f2bfs(fmaxf(acc1[reg], 0.f));
    }

  f32x16 a2 = splat16(b2);
#pragma unroll
  for (int ks2 = 0; ks2 < 4; ++ks2) {
    short8 h = *(const short8*)&hrow[cl][ks2 * 16 + hi * 8];
    short8 w = wf2[ks2 * 64 + lane];
    a2 = __builtin_amdgcn_mfma_f32_32x32x16_bf16(h, w, a2, 0, 0, 0);
  }
  eo = a2;
}

template <int DIV, int LIM>
__device__ __forceinline__ void scatter32(const f32x16& e, int rb, float* eb, int cl, int hi) {
  if (cl < 20) {
#pragma unroll
    for (int g = 0; g < 4; ++g) {
      int r0 = rb + 8 * g + 4 * hi;
      if (r0 / DIV == (r0 + 3) / DIV && r0 + 3 < LIM) {
        atomicAdd(&eb[(r0 / DIV) * 20 + cl],
                  e[4 * g] + e[4 * g + 1] + e[4 * g + 2] + e[4 * g + 3]);
      } else {
#pragma unroll
        for (int q = 0; q < 4; ++q) {
          int rr = r0 + q;
          if (rr < LIM) atomicAdd(&eb[(rr / DIV) * 20 + cl], e[4 * g + q]);
        }
      }
    }
  }
}

// ---------------- fused kernel: one block per batch element ----------------
__global__ __launch_bounds__(256, 3) void fused_kernel(
    const float* __restrict__ x, const float* __restrict__ y,
    const float* __restrict__ Wc, const float* __restrict__ Bc,
    const char* __restrict__ wsb, float* __restrict__ out) {
  __shared__ __align__(16) unsigned char arena_b[ARENA_B];   // 14784 B
  __shared__ __align__(16) short wlds[10240];                // 20480 B, reused per branch
  __shared__ __align__(16) short hlds[4][32][72];            // 18432 B
  __shared__ float osum[24];

  const int b = blockIdx.x;
  const int tid = threadIdx.x;
  const int w = tid >> 6;
  const int lane = tid & 63;
  const int cl = lane & 31, hi = lane >> 5;

  // ---- stage inputs (bf16) + pp weights ----
  {
    short* xb = (short*)(arena_b + XB0);
    for (int k = tid; k < 3600; k += 256) {
      int r = k / 60, c = k - r * 60;
      xb[r * 62 + c] = f2bfs(x[(size_t)b * 3600 + k]);
    }
    short* yb = (short*)(arena_b + YB0);
    if (tid < 70) yb[tid] = f2bfs(y[(size_t)b * 70 + tid]);
    float* ebf = (float*)(arena_b + EBF0);
    for (int k = tid; k < 1200; k += 256) ebf[k] = 0.f;
    if (tid == 0) *(short*)(arena_b + ZS) = 0;
    if (tid < 24) osum[tid] = 0.f;
    uint4* d = (uint4*)wlds;
    const uint4* s = (const uint4*)(wsb + WPP1_B);   // pp stage1+stage2: 20480 B
    for (int k = tid; k < 1280; k += 256) d[k] = s[k];
  }
  __syncthreads();

  const float* biasf = (const float*)(wsb + BIAS_B);
  float* ebf = (float*)(arena_b + EBF0);

  // ================= particle-particle (111 tiles) =================
  {
    const short8* wf1 = (const short8*)wlds;
    const short8* wf2 = (const short8*)wlds + 16 * 64;
    const uint4* tab = (const uint4*)(wsb + TABPP_B);
    float b1a = biasf[0 + cl], b1b = biasf[32 + cl], b2 = biasf[64 + cl];
    for (int mt = w; mt < 111; mt += 4) {
      f32x16 e;
      mlp32<8>(mt, lane, tab, wf1, wf2, b1a, b1b, b2, arena_b, hlds[w], e);
      scatter32<59, 3540>(e, mt * 32, ebf, cl, hi);
    }
  }

  __syncthreads();
  {
    uint4* d = (uint4*)wlds;
    const uint4* s = (const uint4*)(wsb + WPV1_B);   // pv: 14336 B
    for (int k = tid; k < 896; k += 256) d[k] = s[k];
  }
  __syncthreads();

  // ================= particle-vertex (27 tiles) =================
  {
    const short8* wf1 = (const short8*)wlds;
    const short8* wf2 = (const short8*)wlds + 10 * 64;
    const uint4* tab = (const uint4*)(wsb + TABPV_B);
    float b1a = biasf[96 + cl], b1b = biasf[128 + cl], b2 = biasf[160 + cl];
    for (int mt = w; mt < 27; mt += 4) {
      f32x16 e;
      mlp32<5>(mt, lane, tab, wf1, wf2, b1a, b1b, b2, arena_b, hlds[w], e);
      scatter32<14, 840>(e, mt * 32, ebf, cl, hi);
    }
  }

  __syncthreads();  // ebar complete
  {
    short* ebb = (short*)(arena_b + EBB0);
    for (int k = tid; k < 1200; k += 256) ebb[k] = f2bfs(ebf[k]);
    uint4* d = (uint4*)wlds;
    const uint4* s = (const uint4*)(wsb + WO1_B);    // out: 14336 B
    for (int k = tid; k < 896; k += 256) d[k] = s[k];
  }
  __syncthreads();

  // ================= output MLP (2 tiles: waves 0,1) =================
  if (w < 2) {
    const short8* wf1 = (const short8*)wlds;
    const short8* wf2 = (const short8*)wlds + 10 * 64;
    const uint4* tab = (const uint4*)(wsb + TABO_B);
    float b1a = biasf[192 + cl], b1b = biasf[224 + cl], b2 = biasf[256 + cl];
    f32x16 e;
    mlp32<5>(w, lane, tab, wf1, wf2, b1a, b1b, b2, arena_b, hlds[w], e);
    int rb = w * 32;
    if (cl < 24) {
#pragma unroll
      for (int g = 0; g < 4; ++g) {
        int r0 = rb + 8 * g + 4 * hi;
        if (r0 + 3 < 60) {
          atomicAdd(&osum[cl], e[4 * g] + e[4 * g + 1] + e[4 * g + 2] + e[4 * g + 3]);
        } else {
#pragma unroll
          for (int q = 0; q < 4; ++q)
            if (r0 + q < 60) atomicAdd(&osum[cl], e[4 * g + q]);
        }
      }
    }
  }

  __syncthreads();
  if (tid == 0) {
    float sd = Bc[0];
#pragma unroll
    for (int o = 0; o < 24; ++o) sd = fmaf(osum[o], Wc[o], sd);
    out[b] = 1.f / (1.f + expf(-sd));
  }
}

extern "C" void kernel_launch(void* const* d_in, const int* in_sizes, int n_in,
                              void* d_out, int out_size, void* d_ws, size_t ws_size,
                              hipStream_t stream) {
  const float* x     = (const float*)d_in[0];
  const float* y     = (const float*)d_in[1];
  const float* W1_pp = (const float*)d_in[2];
  const float* b1_pp = (const float*)d_in[3];
  const float* W2_pp = (const float*)d_in[4];
  const float* b2_pp = (const float*)d_in[5];
  const float* W1_pv = (const float*)d_in[6];
  const float* b1_pv = (const float*)d_in[7];
  const float* W2_pv = (const float*)d_in[8];
  const float* b2_pv = (const float*)d_in[9];
  const float* W1_o  = (const float*)d_in[10];
  const float* b1_o  = (const float*)d_in[11];
  const float* W2_o  = (const float*)d_in[12];
  const float* b2_o  = (const float*)d_in[13];
  const float* Wc    = (const float*)d_in[14];
  const float* bc    = (const float*)d_in[15];
  float* out = (float*)d_out;
  char* wsb = (char*)d_ws;

  const int Bb = in_sizes[0] / 3600;  // 1024
  const int tab_total = NTAB_PP + NTAB_PV + NTAB_O;  // 528896

  build_tables<<<(tab_total + 255) / 256, 256, 0, stream>>>(wsb);
  build_wfrag<<<(12288 + 288 + 255) / 256, 256, 0, stream>>>(wsb,
      W1_pp, W2_pp, W1_pv, W2_pv, W1_o, W2_o,
      b1_pp, b2_pp, b1_pv, b2_pv, b1_o, b2_o);
  fused_kernel<<<Bb, 256, 0, stream>>>(x, y, Wc, bc, wsb, out);
}

// Round 9
// 353.945 us; speedup vs baseline: 1.0792x; 1.0792x over previous
//
#include <hip/hip_runtime.h>
#include <hip/hip_bf16.h>
#include <math.h>

typedef __attribute__((ext_vector_type(8))) short short8;
typedef __attribute__((ext_vector_type(4))) float f32x4;

namespace {
// ---- merged shared-memory BYTE layout (one block, u16-addressable) ----
constexpr int XB0    = 0;       // x bf16 [60][62] = 7440
constexpr int YB0    = 7440;    // y bf16 [5][14] = 140
constexpr int ZSB    = 7580;    // zero u16
constexpr int EBF_B  = 7584;    // ebar f32 [60][20] = 4800
constexpr int WLDS_B = 12384;   // stage-1 weight frags (<=16 KB), reused per branch
constexpr int EBB_B  = 24672;   // ebar bf16 [60][20] = 2400 (over pv-frag area, out phase only)
constexpr int HLDS_B = 28768;   // 4 waves x [16][72] bf16 = 9216
constexpr int OSUM_B = 37984;   // f32[24]
constexpr int SM_BYTES = 38080;

// ---- ws byte offsets ----
constexpr int NTAB_PP = 222 * 4 * 64 * 8;   // u16 entries
constexpr int NTAB_PV = 53 * 3 * 64 * 8;
constexpr int NTAB_O  = 4 * 3 * 64 * 8;
constexpr int TABPP_B = 0;
constexpr int TABPV_B = TABPP_B + NTAB_PP * 2;   // 909312
constexpr int TABO_B  = TABPV_B + NTAB_PV * 2;   // 1072128
constexpr int WPP1_B  = TABO_B + NTAB_O * 2;     // 1084416, 16 frags (1 KB each)
constexpr int WPP2_B  = WPP1_B + 16 * 1024;
constexpr int WPV1_B  = WPP2_B + 4 * 1024;       // 12 frags
constexpr int WPV2_B  = WPV1_B + 12 * 1024;
constexpr int WO1_B   = WPV2_B + 4 * 1024;       // 12 frags
constexpr int WO2_B   = WO1_B + 12 * 1024;
constexpr int BIAS_B  = WO2_B + 4 * 1024;        // 288 f32
}

__device__ __forceinline__ short f2bfs(float f) {
  __hip_bfloat16 h = __float2bfloat16(f);
  short s;
  __builtin_memcpy(&s, &h, 2);
  return s;
}

// ---------------- init: gather tables (u16 BYTE offsets into merged SM) ----------------
__global__ __launch_bounds__(256) void build_tables(char* wsb) {
  int t = blockIdx.x * 256 + threadIdx.x;
  unsigned short* tpp = (unsigned short*)(wsb + TABPP_B);
  unsigned short* tpv = (unsigned short*)(wsb + TABPV_B);
  unsigned short* tou = (unsigned short*)(wsb + TABO_B);
  if (t < NTAB_PP) {
    int j = t & 7, l = (t >> 3) & 63, blk = t >> 9;
    int ks = blk & 3, mt = blk >> 2;
    int rr = mt * 16 + (l & 15), k = ks * 32 + (l >> 4) * 8 + j;
    unsigned off = ZSB;
    if (rr < 3540 && k < 120) {
      unsigned p = (unsigned)rr * 120u + (unsigned)k;
      unsigned f = p / 3540u, e = p - f * 3540u;
      unsigned i = e / 59u, jj = e - i * 59u;
      unsigned col = (f < 60u) ? i : ((jj < i) ? jj : jj + 1u);
      unsigned ft = (f < 60u) ? f : f - 60u;
      off = XB0 + (ft * 62u + col) * 2u;
    }
    tpp[t] = (unsigned short)off;
    return;
  }
  t -= NTAB_PP;
  if (t < NTAB_PV) {
    int j = t & 7, l = (t >> 3) & 63, blk = t >> 9;
    int ks = blk % 3, mt = blk / 3;
    int tt = mt * 16 + (l & 15), k = ks * 32 + (l >> 4) * 8 + j;
    unsigned off = ZSB;
    if (tt < 840 && k < 65) {
      int i = tt / 14, v = tt - i * 14;
      off = (k < 60) ? (unsigned)(XB0 + (k * 62 + i) * 2)
                     : (unsigned)(YB0 + ((k - 60) * 14 + v) * 2);
    }
    tpv[t] = (unsigned short)off;
    return;
  }
  t -= NTAB_PV;
  if (t < NTAB_O) {
    int j = t & 7, l = (t >> 3) & 63, blk = t >> 9;
    int ks = blk % 3, mt = blk / 3;
    int r = mt * 16 + (l & 15), k = ks * 32 + (l >> 4) * 8 + j;
    unsigned off = ZSB;
    if (r < 60 && k < 80)
      off = (k < 60) ? (unsigned)(XB0 + (r * 62 + k) * 2)
                     : (unsigned)(EBB_B + (r * 20 + (k - 60)) * 2);
    tou[t] = (unsigned short)off;
  }
}

// ---------------- init: weight fragments (bf16, 16x16x32 B-layout) + biases ----------------
// B-frag: lane l holds B[k = ks*32 + (l>>4)*8 + 2d(+1)][n = nt*16 + (l&15)]
__global__ __launch_bounds__(256) void build_wfrag(char* wsb,
    const float* W1pp, const float* W2pp, const float* W1pv, const float* W2pv,
    const float* W1o, const float* W2o,
    const float* b1pp, const float* b2pp, const float* b1pv, const float* b2pv,
    const float* b1o, const float* b2o) {
  int t = blockIdx.x * 256 + threadIdx.x;
  if (t < 13312) {
    const float* W; int Kt, Nt, NTt; unsigned* dst; int local;
    if (t < 4096)       { W = W1pp; Kt = 120; Nt = 60; NTt = 4; dst = (unsigned*)(wsb + WPP1_B); local = t; }
    else if (t < 5120)  { W = W2pp; Kt = 60;  Nt = 20; NTt = 2; dst = (unsigned*)(wsb + WPP2_B); local = t - 4096; }
    else if (t < 8192)  { W = W1pv; Kt = 65;  Nt = 60; NTt = 4; dst = (unsigned*)(wsb + WPV1_B); local = t - 5120; }
    else if (t < 9216)  { W = W2pv; Kt = 60;  Nt = 20; NTt = 2; dst = (unsigned*)(wsb + WPV2_B); local = t - 8192; }
    else if (t < 12288) { W = W1o;  Kt = 80;  Nt = 60; NTt = 4; dst = (unsigned*)(wsb + WO1_B);  local = t - 9216; }
    else                { W = W2o;  Kt = 60;  Nt = 24; NTt = 2; dst = (unsigned*)(wsb + WO2_B);  local = t - 12288; }
    int d = local & 3, l = (local >> 2) & 63, rest = local >> 8;
    int nt = rest % NTt, ks = rest / NTt;
    int k = ks * 32 + (l >> 4) * 8 + 2 * d, n = nt * 16 + (l & 15);
    float v0 = (k < Kt && n < Nt) ? W[k * Nt + n] : 0.f;
    float v1 = (k + 1 < Kt && n < Nt) ? W[(k + 1) * Nt + n] : 0.f;
    unsigned u0 = (unsigned short)f2bfs(v0);
    unsigned u1 = (unsigned short)f2bfs(v1);
    dst[local] = u0 | (u1 << 16);
    return;
  }
  t -= 13312;
  if (t < 288) {
    float* bd = (float*)(wsb + BIAS_B);
    float v = 0.f;
    if (t < 64)       { if (t < 60) v = b1pp[t]; }
    else if (t < 96)  { int n = t - 64;  if (n < 20) v = b2pp[n]; }
    else if (t < 160) { int n = t - 96;  if (n < 60) v = b1pv[n]; }
    else if (t < 192) { int n = t - 160; if (n < 20) v = b2pv[n]; }
    else if (t < 256) { int n = t - 192; if (n < 60) v = b1o[n]; }
    else              { int n = t - 256; if (n < 24) v = b2o[n]; }
    bd[t] = v;
  }
}

// ---- one 16-row M-tile: gathered-A stage1 (weights LDS) -> relu -> H LDS -> stage2 (weights regs) ----
// A-frag: lane holds A[m=l&15][k=(l>>4)*8+j]; C/D: col=l&15, row=(l>>4)*4+reg.
template <int NKS>
__device__ __forceinline__ void mlp_core(
    const uint4 (&tw)[NKS], int lane,
    const short8* wf1,                 // LDS stage-1 frags
    const short8 (&wf2r)[4],           // stage-2 frags in registers
    const float (&b1v)[4], const float (&b2v)[2],
    const unsigned char* smb, short (*hrow)[72], f32x4 (&a2)[2])
{
  const int cl = lane & 15, qq = lane >> 4;

  f32x4 acc[4];
#pragma unroll
  for (int nt = 0; nt < 4; ++nt) {
    float bv = b1v[nt];
    acc[nt] = (f32x4){bv, bv, bv, bv};
  }

#pragma unroll
  for (int ks = 0; ks < NKS; ++ks) {
    short8 af;
    af[0] = *(const short*)(smb + (tw[ks].x & 0xffffu));
    af[1] = *(const short*)(smb + (tw[ks].x >> 16));
    af[2] = *(const short*)(smb + (tw[ks].y & 0xffffu));
    af[3] = *(const short*)(smb + (tw[ks].y >> 16));
    af[4] = *(const short*)(smb + (tw[ks].z & 0xffffu));
    af[5] = *(const short*)(smb + (tw[ks].z >> 16));
    af[6] = *(const short*)(smb + (tw[ks].w & 0xffffu));
    af[7] = *(const short*)(smb + (tw[ks].w >> 16));
#pragma unroll
    for (int nt = 0; nt < 4; ++nt) {
      short8 wf = wf1[(ks * 4 + nt) * 64 + lane];
      acc[nt] = __builtin_amdgcn_mfma_f32_16x16x32_bf16(af, wf, acc[nt], 0, 0, 0);
    }
  }

  // relu -> per-wave H tile (bf16, rows padded to 72 shorts = 144 B)
#pragma unroll
  for (int nt = 0; nt < 4; ++nt)
#pragma unroll
    for (int r = 0; r < 4; ++r)
      hrow[qq * 4 + r][nt * 16 + cl] = f2bfs(fmaxf(acc[nt][r], 0.f));

#pragma unroll
  for (int nt = 0; nt < 2; ++nt) {
    float bv = b2v[nt];
    a2[nt] = (f32x4){bv, bv, bv, bv};
  }
#pragma unroll
  for (int k2 = 0; k2 < 2; ++k2) {
    short8 h = *(const short8*)&hrow[cl][k2 * 32 + qq * 8];
#pragma unroll
    for (int nt = 0; nt < 2; ++nt)
      a2[nt] = __builtin_amdgcn_mfma_f32_16x16x32_bf16(h, wf2r[k2 * 2 + nt], a2[nt], 0, 0, 0);
  }
}

template <int DIV, int LIM>
__device__ __forceinline__ void scatter_e(const f32x4 (&a2)[2], int rb, float* eb, int cl) {
  int riA = rb / DIV, riB = (rb + 3) / DIV;
#pragma unroll
  for (int nt = 0; nt < 2; ++nt) {
    int col = nt * 16 + cl;
    if (col < 20) {
      if (riA == riB && rb + 3 < LIM) {
        atomicAdd(&eb[riA * 20 + col], a2[nt][0] + a2[nt][1] + a2[nt][2] + a2[nt][3]);
      } else {
#pragma unroll
        for (int r = 0; r < 4; ++r) {
          int rr = rb + r;
          if (rr < LIM) atomicAdd(&eb[(rr / DIV) * 20 + col], a2[nt][r]);
        }
      }
    }
  }
}

// ---------------- fused kernel: one block per batch element, 4 blocks/CU ----------------
__global__ __launch_bounds__(256, 4) void fused_kernel(
    const float* __restrict__ x, const float* __restrict__ y,
    const float* __restrict__ Wc, const float* __restrict__ Bc,
    const char* __restrict__ wsb, float* __restrict__ out) {
  __shared__ __align__(16) unsigned char SM[SM_BYTES];

  const int b = blockIdx.x;
  const int tid = threadIdx.x;
  const int w = tid >> 6;
  const int lane = tid & 63;
  const int cl = lane & 15, q4 = (lane >> 4) * 4;

  float* ebf = (float*)(SM + EBF_B);
  float* osum = (float*)(SM + OSUM_B);
  short (*hrow)[72] = (short(*)[72])(SM + HLDS_B + w * 2304);
  const float* biasf = (const float*)(wsb + BIAS_B);

  // ---- stage inputs (bf16) + pp stage-1 weights ----
  {
    short* xb = (short*)(SM + XB0);
    for (int k = tid; k < 3600; k += 256) {
      int r = k / 60, c = k - r * 60;
      xb[r * 62 + c] = f2bfs(x[(size_t)b * 3600 + k]);
    }
    short* yb = (short*)(SM + YB0);
    if (tid < 70) yb[tid] = f2bfs(y[(size_t)b * 70 + tid]);
    if (tid == 0) *(short*)(SM + ZSB) = 0;
    for (int k = tid; k < 1200; k += 256) ebf[k] = 0.f;
    if (tid < 24) osum[tid] = 0.f;
    uint4* d = (uint4*)(SM + WLDS_B);
    const uint4* s = (const uint4*)(wsb + WPP1_B);   // 16 KB
    for (int k = tid; k < 1024; k += 256) d[k] = s[k];
  }
  __syncthreads();

  // ================= particle-particle (222 tiles of 16 rows) =================
  {
    const short8* wf1 = (const short8*)(SM + WLDS_B);
    const uint4* tab = (const uint4*)(wsb + TABPP_B);
    short8 wf2r[4];
#pragma unroll
    for (int i = 0; i < 4; ++i) wf2r[i] = ((const short8*)(wsb + WPP2_B))[i * 64 + lane];
    float b1v[4], b2v[2];
#pragma unroll
    for (int nt = 0; nt < 4; ++nt) b1v[nt] = biasf[0 + nt * 16 + cl];
#pragma unroll
    for (int nt = 0; nt < 2; ++nt) b2v[nt] = biasf[64 + nt * 16 + cl];

    uint4 twn[4];
#pragma unroll
    for (int ks = 0; ks < 4; ++ks) twn[ks] = tab[(w * 4 + ks) * 64 + lane];
    for (int mt = w; mt < 222; mt += 4) {
      uint4 twc[4];
#pragma unroll
      for (int ks = 0; ks < 4; ++ks) twc[ks] = twn[ks];
      int mtn = mt + 4;
      if (mtn < 222) {
#pragma unroll
        for (int ks = 0; ks < 4; ++ks) twn[ks] = tab[(mtn * 4 + ks) * 64 + lane];
      }
      f32x4 a2[2];
      mlp_core<4>(twc, lane, wf1, wf2r, b1v, b2v, SM, hrow, a2);
      scatter_e<59, 3540>(a2, mt * 16 + q4, ebf, cl);
    }
  }

  __syncthreads();
  {
    uint4* d = (uint4*)(SM + WLDS_B);
    const uint4* s = (const uint4*)(wsb + WPV1_B);   // 12 KB
    for (int k = tid; k < 768; k += 256) d[k] = s[k];
  }
  __syncthreads();

  // ================= particle-vertex (53 tiles) =================
  {
    const short8* wf1 = (const short8*)(SM + WLDS_B);
    const uint4* tab = (const uint4*)(wsb + TABPV_B);
    short8 wf2r[4];
#pragma unroll
    for (int i = 0; i < 4; ++i) wf2r[i] = ((const short8*)(wsb + WPV2_B))[i * 64 + lane];
    float b1v[4], b2v[2];
#pragma unroll
    for (int nt = 0; nt < 4; ++nt) b1v[nt] = biasf[96 + nt * 16 + cl];
#pragma unroll
    for (int nt = 0; nt < 2; ++nt) b2v[nt] = biasf[160 + nt * 16 + cl];

    uint4 twn[3];
    if (w < 53) {
#pragma unroll
      for (int ks = 0; ks < 3; ++ks) twn[ks] = tab[(w * 3 + ks) * 64 + lane];
    }
    for (int mt = w; mt < 53; mt += 4) {
      uint4 twc[3];
#pragma unroll
      for (int ks = 0; ks < 3; ++ks) twc[ks] = twn[ks];
      int mtn = mt + 4;
      if (mtn < 53) {
#pragma unroll
        for (int ks = 0; ks < 3; ++ks) twn[ks] = tab[(mtn * 3 + ks) * 64 + lane];
      }
      f32x4 a2[2];
      mlp_core<3>(twc, lane, wf1, wf2r, b1v, b2v, SM, hrow, a2);
      scatter_e<14, 840>(a2, mt * 16 + q4, ebf, cl);
    }
  }

  __syncthreads();  // ebar complete; pv weight reads done
  {
    short* ebb = (short*)(SM + EBB_B);
    for (int k = tid; k < 1200; k += 256) ebb[k] = f2bfs(ebf[k]);
    uint4* d = (uint4*)(SM + WLDS_B);
    const uint4* s = (const uint4*)(wsb + WO1_B);    // 12 KB (disjoint from EBB region)
    for (int k = tid; k < 768; k += 256) d[k] = s[k];
  }
  __syncthreads();

  // ================= output MLP (4 tiles, one per wave) =================
  {
    const short8* wf1 = (const short8*)(SM + WLDS_B);
    const uint4* tab = (const uint4*)(wsb + TABO_B);
    short8 wf2r[4];
#pragma unroll
    for (int i = 0; i < 4; ++i) wf2r[i] = ((const short8*)(wsb + WO2_B))[i * 64 + lane];
    float b1v[4], b2v[2];
#pragma unroll
    for (int nt = 0; nt < 4; ++nt) b1v[nt] = biasf[192 + nt * 16 + cl];
#pragma unroll
    for (int nt = 0; nt < 2; ++nt) b2v[nt] = biasf[256 + nt * 16 + cl];

    uint4 twc[3];
#pragma unroll
    for (int ks = 0; ks < 3; ++ks) twc[ks] = tab[(w * 3 + ks) * 64 + lane];
    f32x4 a2[2];
    mlp_core<3>(twc, lane, wf1, wf2r, b1v, b2v, SM, hrow, a2);

    int rb = w * 16 + q4;
#pragma unroll
    for (int nt = 0; nt < 2; ++nt) {
      int col = nt * 16 + cl;
      if (col < 24) {
        if (rb + 3 < 60) {
          atomicAdd(&osum[col], a2[nt][0] + a2[nt][1] + a2[nt][2] + a2[nt][3]);
        } else {
#pragma unroll
          for (int r = 0; r < 4; ++r)
            if (rb + r < 60) atomicAdd(&osum[col], a2[nt][r]);
        }
      }
    }
  }

  __syncthreads();
  if (tid == 0) {
    float sd = Bc[0];
#pragma unroll
    for (int o = 0; o < 24; ++o) sd = fmaf(osum[o], Wc[o], sd);
    out[b] = 1.f / (1.f + expf(-sd));
  }
}

extern "C" void kernel_launch(void* const* d_in, const int* in_sizes, int n_in,
                              void* d_out, int out_size, void* d_ws, size_t ws_size,
                              hipStream_t stream) {
  const float* x     = (const float*)d_in[0];
  const float* y     = (const float*)d_in[1];
  const float* W1_pp = (const float*)d_in[2];
  const float* b1_pp = (const float*)d_in[3];
  const float* W2_pp = (const float*)d_in[4];
  const float* b2_pp = (const float*)d_in[5];
  const float* W1_pv = (const float*)d_in[6];
  const float* b1_pv = (const float*)d_in[7];
  const float* W2_pv = (const float*)d_in[8];
  const float* b2_pv = (const float*)d_in[9];
  const float* W1_o  = (const float*)d_in[10];
  const float* b1_o  = (const float*)d_in[11];
  const float* W2_o  = (const float*)d_in[12];
  const float* b2_o  = (const float*)d_in[13];
  const float* Wc    = (const float*)d_in[14];
  const float* bc    = (const float*)d_in[15];
  float* out = (float*)d_out;
  char* wsb = (char*)d_ws;

  const int Bb = in_sizes[0] / 3600;  // 1024
  const int tab_total = NTAB_PP + NTAB_PV + NTAB_O;  // 542208

  build_tables<<<(tab_total + 255) / 256, 256, 0, stream>>>(wsb);
  build_wfrag<<<(13312 + 288 + 255) / 256, 256, 0, stream>>>(wsb,
      W1_pp, W2_pp, W1_pv, W2_pv, W1_o, W2_o,
      b1_pp, b2_pp, b1_pv, b2_pv, b1_o, b2_o);
  fused_kernel<<<Bb, 256, 0, stream>>>(x, y, Wc, bc, wsb, out);
}

// Round 10
// 314.738 us; speedup vs baseline: 1.2136x; 1.1246x over previous
//
#include <hip/hip_runtime.h>
#include <hip/hip_bf16.h>
#include <math.h>

typedef __attribute__((ext_vector_type(8))) short short8;
typedef __attribute__((ext_vector_type(4))) short short4v;
typedef __attribute__((ext_vector_type(4))) float f32x4;
typedef __attribute__((ext_vector_type(4))) unsigned int u32x4;

namespace {
// ---- merged shared-memory BYTE layout ----
constexpr int XB0    = 0;       // x bf16 [60][62] = 7440
constexpr int YB0    = 7440;    // y bf16 [5][14] = 140
constexpr int ZSB    = 7580;    // zero u16
constexpr int EBF_B  = 7584;    // ebar f32 [60][20] = 4800
constexpr int EBB_B  = 12384;   // ebar bf16 [60][20] = 2400
constexpr int HLDS_B = 14784;   // 4 waves x [16][72] bf16 = 9216
constexpr int OSUM_B = 24000;   // f32[24]
constexpr int SM_BYTES = 24096;

// ---- ws byte offsets ----
constexpr int NTAB_PP = 222 * 4 * 64 * 8;   // u16 entries
constexpr int NTAB_PV = 53 * 3 * 64 * 8;
constexpr int NTAB_O  = 4 * 3 * 64 * 8;
constexpr int TABPP_B = 0;
constexpr int TABPV_B = TABPP_B + NTAB_PP * 2;   // 909312
constexpr int TABO_B  = TABPV_B + NTAB_PV * 2;   // 1072128
constexpr int WPP1_B  = TABO_B + NTAB_O * 2;     // 1084416, 16 frags (1 KB each)
constexpr int WPP2_B  = WPP1_B + 16 * 1024;
constexpr int WPV1_B  = WPP2_B + 4 * 1024;       // 12 frags
constexpr int WPV2_B  = WPV1_B + 12 * 1024;
constexpr int WO1_B   = WPV2_B + 4 * 1024;       // 12 frags
constexpr int WO2_B   = WO1_B + 12 * 1024;
constexpr int BIAS_B  = WO2_B + 4 * 1024;        // 288 f32
}

__device__ __forceinline__ short f2bfs(float f) {
  __hip_bfloat16 h = __float2bfloat16(f);
  short s;
  __builtin_memcpy(&s, &h, 2);
  return s;
}

__device__ __forceinline__ short8 as_s8(u32x4 v) {
  short8 s;
  __builtin_memcpy(&s, &v, 16);
  return s;
}

// ---------------- init: gather tables (u16 BYTE offsets into merged SM) ----------------
__global__ __launch_bounds__(256) void build_tables(char* wsb) {
  int t = blockIdx.x * 256 + threadIdx.x;
  unsigned short* tpp = (unsigned short*)(wsb + TABPP_B);
  unsigned short* tpv = (unsigned short*)(wsb + TABPV_B);
  unsigned short* tou = (unsigned short*)(wsb + TABO_B);
  if (t < NTAB_PP) {
    int j = t & 7, l = (t >> 3) & 63, blk = t >> 9;
    int ks = blk & 3, mt = blk >> 2;
    int rr = mt * 16 + (l & 15), k = ks * 32 + (l >> 4) * 8 + j;
    unsigned off = ZSB;
    if (rr < 3540 && k < 120) {
      unsigned p = (unsigned)rr * 120u + (unsigned)k;
      unsigned f = p / 3540u, e = p - f * 3540u;
      unsigned i = e / 59u, jj = e - i * 59u;
      unsigned col = (f < 60u) ? i : ((jj < i) ? jj : jj + 1u);
      unsigned ft = (f < 60u) ? f : f - 60u;
      off = XB0 + (ft * 62u + col) * 2u;
    }
    tpp[t] = (unsigned short)off;
    return;
  }
  t -= NTAB_PP;
  if (t < NTAB_PV) {
    int j = t & 7, l = (t >> 3) & 63, blk = t >> 9;
    int ks = blk % 3, mt = blk / 3;
    int tt = mt * 16 + (l & 15), k = ks * 32 + (l >> 4) * 8 + j;
    unsigned off = ZSB;
    if (tt < 840 && k < 65) {
      int i = tt / 14, v = tt - i * 14;
      off = (k < 60) ? (unsigned)(XB0 + (k * 62 + i) * 2)
                     : (unsigned)(YB0 + ((k - 60) * 14 + v) * 2);
    }
    tpv[t] = (unsigned short)off;
    return;
  }
  t -= NTAB_PV;
  if (t < NTAB_O) {
    int j = t & 7, l = (t >> 3) & 63, blk = t >> 9;
    int ks = blk % 3, mt = blk / 3;
    int r = mt * 16 + (l & 15), k = ks * 32 + (l >> 4) * 8 + j;
    unsigned off = ZSB;
    if (r < 60 && k < 80)
      off = (k < 60) ? (unsigned)(XB0 + (r * 62 + k) * 2)
                     : (unsigned)(EBB_B + (r * 20 + (k - 60)) * 2);
    tou[t] = (unsigned short)off;
  }
}

// ---------------- init: weight fragments (bf16, 16x16x32 B-layout) + biases ----------------
// Stage-1 B-frag: lane l holds B[k = ks*32+(l>>4)*8+2d(+1)][n = nt*16+(l&15)]
// Stage-2: same, but k-dim PERMUTED to match packed-H layout: orig_h(k') = (k'&3)*16 + (k'>>2)
__global__ __launch_bounds__(256) void build_wfrag(char* wsb,
    const float* W1pp, const float* W2pp, const float* W1pv, const float* W2pv,
    const float* W1o, const float* W2o,
    const float* b1pp, const float* b2pp, const float* b1pv, const float* b2pv,
    const float* b1o, const float* b2o) {
  int t = blockIdx.x * 256 + threadIdx.x;
  if (t < 13312) {
    const float* W; int Kt, Nt, NTt; unsigned* dst; int local; bool st2;
    if (t < 4096)       { W = W1pp; Kt = 120; Nt = 60; NTt = 4; dst = (unsigned*)(wsb + WPP1_B); local = t; st2 = false; }
    else if (t < 5120)  { W = W2pp; Kt = 60;  Nt = 20; NTt = 2; dst = (unsigned*)(wsb + WPP2_B); local = t - 4096; st2 = true; }
    else if (t < 8192)  { W = W1pv; Kt = 65;  Nt = 60; NTt = 4; dst = (unsigned*)(wsb + WPV1_B); local = t - 5120; st2 = false; }
    else if (t < 9216)  { W = W2pv; Kt = 60;  Nt = 20; NTt = 2; dst = (unsigned*)(wsb + WPV2_B); local = t - 8192; st2 = true; }
    else if (t < 12288) { W = W1o;  Kt = 80;  Nt = 60; NTt = 4; dst = (unsigned*)(wsb + WO1_B);  local = t - 9216; st2 = false; }
    else                { W = W2o;  Kt = 60;  Nt = 24; NTt = 2; dst = (unsigned*)(wsb + WO2_B);  local = t - 12288; st2 = true; }
    int d = local & 3, l = (local >> 2) & 63, rest = local >> 8;
    int nt = rest % NTt, ks = rest / NTt;
    int k0 = ks * 32 + (l >> 4) * 8 + 2 * d, k1 = k0 + 1;
    if (st2) {                      // permuted k for packed-H layout
      k0 = (k0 & 3) * 16 + (k0 >> 2);
      k1 = (k1 & 3) * 16 + (k1 >> 2);
    }
    int n = nt * 16 + (l & 15);
    float v0 = (k0 < Kt && n < Nt) ? W[k0 * Nt + n] : 0.f;
    float v1 = (k1 < Kt && n < Nt) ? W[k1 * Nt + n] : 0.f;
    unsigned u0 = (unsigned short)f2bfs(v0);
    unsigned u1 = (unsigned short)f2bfs(v1);
    dst[local] = u0 | (u1 << 16);
    return;
  }
  t -= 13312;
  if (t < 288) {
    float* bd = (float*)(wsb + BIAS_B);
    float v = 0.f;
    if (t < 64)       { if (t < 60) v = b1pp[t]; }
    else if (t < 96)  { int n = t - 64;  if (n < 20) v = b2pp[n]; }
    else if (t < 160) { int n = t - 96;  if (n < 60) v = b1pv[n]; }
    else if (t < 192) { int n = t - 160; if (n < 20) v = b2pv[n]; }
    else if (t < 256) { int n = t - 192; if (n < 60) v = b1o[n]; }
    else              { int n = t - 256; if (n < 24) v = b2o[n]; }
    bd[t] = v;
  }
}

// ---- one 16-row M-tile: gathered-A stage1 (weights in regs) -> relu -> packed H -> stage2 ----
// A-frag: lane holds A[m=l&15][k=(l>>4)*8+j]; C/D: col=l&15, row=(l>>4)*4+reg.
template <int NKS>
__device__ __forceinline__ void mlp_core(
    const uint4 (&tw)[NKS], int lane,
    const u32x4 (&wf1r)[NKS * 4], const u32x4 (&wf2r)[4],
    const float (&b1v)[4], const float (&b2v)[2],
    const unsigned char* smb, short (*hrow)[72], f32x4 (&a2)[2])
{
  const int cl = lane & 15, qq = lane >> 4;

  f32x4 acc[4];
#pragma unroll
  for (int nt = 0; nt < 4; ++nt) {
    float bv = b1v[nt];
    acc[nt] = (f32x4){bv, bv, bv, bv};
  }

#pragma unroll
  for (int ks = 0; ks < NKS; ++ks) {
    short8 af;
    af[0] = *(const short*)(smb + (tw[ks].x & 0xffffu));
    af[1] = *(const short*)(smb + (tw[ks].x >> 16));
    af[2] = *(const short*)(smb + (tw[ks].y & 0xffffu));
    af[3] = *(const short*)(smb + (tw[ks].y >> 16));
    af[4] = *(const short*)(smb + (tw[ks].z & 0xffffu));
    af[5] = *(const short*)(smb + (tw[ks].z >> 16));
    af[6] = *(const short*)(smb + (tw[ks].w & 0xffffu));
    af[7] = *(const short*)(smb + (tw[ks].w >> 16));
#pragma unroll
    for (int nt = 0; nt < 4; ++nt)
      acc[nt] = __builtin_amdgcn_mfma_f32_16x16x32_bf16(af, as_s8(wf1r[ks * 4 + nt]), acc[nt], 0, 0, 0);
  }

  // relu -> packed H write: h' = cl*4 + nt, one b64 per row
#pragma unroll
  for (int r = 0; r < 4; ++r) {
    short4v hw;
    hw[0] = f2bfs(fmaxf(acc[0][r], 0.f));
    hw[1] = f2bfs(fmaxf(acc[1][r], 0.f));
    hw[2] = f2bfs(fmaxf(acc[2][r], 0.f));
    hw[3] = f2bfs(fmaxf(acc[3][r], 0.f));
    *(short4v*)&hrow[qq * 4 + r][cl * 4] = hw;
  }

#pragma unroll
  for (int nt = 0; nt < 2; ++nt) {
    float bv = b2v[nt];
    a2[nt] = (f32x4){bv, bv, bv, bv};
  }
#pragma unroll
  for (int k2 = 0; k2 < 2; ++k2) {
    short8 h = *(const short8*)&hrow[cl][k2 * 32 + qq * 8];
#pragma unroll
    for (int nt = 0; nt < 2; ++nt)
      a2[nt] = __builtin_amdgcn_mfma_f32_16x16x32_bf16(h, as_s8(wf2r[k2 * 2 + nt]), a2[nt], 0, 0, 0);
  }
}

template <int DIV, int LIM>
__device__ __forceinline__ void scatter_e(const f32x4 (&a2)[2], int rb, float* eb, int cl) {
  int riA = rb / DIV, riB = (rb + 3) / DIV;
#pragma unroll
  for (int nt = 0; nt < 2; ++nt) {
    int col = nt * 16 + cl;
    if (col < 20) {
      if (riA == riB && rb + 3 < LIM) {
        atomicAdd(&eb[riA * 20 + col], a2[nt][0] + a2[nt][1] + a2[nt][2] + a2[nt][3]);
      } else {
#pragma unroll
        for (int r = 0; r < 4; ++r) {
          int rr = rb + r;
          if (rr < LIM) atomicAdd(&eb[(rr / DIV) * 20 + col], a2[nt][r]);
        }
      }
    }
  }
}

// load NF weight frags into registers and PIN them (asm keep-alive: unrematerializable)
template <int NF>
__device__ __forceinline__ void load_pin(u32x4 (&r)[NF], const char* src, int lane) {
#pragma unroll
  for (int i = 0; i < NF; ++i) r[i] = ((const u32x4*)src)[i * 64 + lane];
#pragma unroll
  for (int i = 0; i < NF; ++i) asm volatile("" : "+v"(r[i]));
}

// ---------------- fused kernel: one block per batch element ----------------
__global__ __launch_bounds__(256, 3) void fused_kernel(
    const float* __restrict__ x, const float* __restrict__ y,
    const float* __restrict__ Wc, const float* __restrict__ Bc,
    const char* __restrict__ wsb, float* __restrict__ out) {
  __shared__ __align__(16) unsigned char SM[SM_BYTES];

  const int b = blockIdx.x;
  const int tid = threadIdx.x;
  const int w = tid >> 6;
  const int lane = tid & 63;
  const int cl = lane & 15, q4 = (lane >> 4) * 4;

  float* ebf = (float*)(SM + EBF_B);
  float* osum = (float*)(SM + OSUM_B);
  short (*hrow)[72] = (short(*)[72])(SM + HLDS_B + w * 2304);
  const float* biasf = (const float*)(wsb + BIAS_B);

  // ---- stage inputs (bf16) ----
  {
    short* xb = (short*)(SM + XB0);
    for (int k = tid; k < 3600; k += 256) {
      int r = k / 60, c = k - r * 60;
      xb[r * 62 + c] = f2bfs(x[(size_t)b * 3600 + k]);
    }
    short* yb = (short*)(SM + YB0);
    if (tid < 70) yb[tid] = f2bfs(y[(size_t)b * 70 + tid]);
    if (tid == 0) *(short*)(SM + ZSB) = 0;
    for (int k = tid; k < 1200; k += 256) ebf[k] = 0.f;
    if (tid < 24) osum[tid] = 0.f;
  }
  __syncthreads();

  // ================= particle-particle (222 tiles of 16 rows) =================
  {
    const uint4* tab = (const uint4*)(wsb + TABPP_B);
    u32x4 wf1r[16], wf2r[4];
    load_pin<16>(wf1r, wsb + WPP1_B, lane);
    load_pin<4>(wf2r, wsb + WPP2_B, lane);
    float b1v[4], b2v[2];
#pragma unroll
    for (int nt = 0; nt < 4; ++nt) b1v[nt] = biasf[0 + nt * 16 + cl];
#pragma unroll
    for (int nt = 0; nt < 2; ++nt) b2v[nt] = biasf[64 + nt * 16 + cl];

    uint4 twn[4];
#pragma unroll
    for (int ks = 0; ks < 4; ++ks) twn[ks] = tab[(w * 4 + ks) * 64 + lane];
    for (int mt = w; mt < 222; mt += 4) {
      uint4 twc[4];
#pragma unroll
      for (int ks = 0; ks < 4; ++ks) twc[ks] = twn[ks];
      int mtn = mt + 4;
      if (mtn < 222) {
#pragma unroll
        for (int ks = 0; ks < 4; ++ks) twn[ks] = tab[(mtn * 4 + ks) * 64 + lane];
      }
      f32x4 a2[2];
      mlp_core<4>(twc, lane, wf1r, wf2r, b1v, b2v, SM, hrow, a2);
      scatter_e<59, 3540>(a2, mt * 16 + q4, ebf, cl);
    }
  }

  __syncthreads();

  // ================= particle-vertex (53 tiles) =================
  {
    const uint4* tab = (const uint4*)(wsb + TABPV_B);
    u32x4 wf1r[12], wf2r[4];
    load_pin<12>(wf1r, wsb + WPV1_B, lane);
    load_pin<4>(wf2r, wsb + WPV2_B, lane);
    float b1v[4], b2v[2];
#pragma unroll
    for (int nt = 0; nt < 4; ++nt) b1v[nt] = biasf[96 + nt * 16 + cl];
#pragma unroll
    for (int nt = 0; nt < 2; ++nt) b2v[nt] = biasf[160 + nt * 16 + cl];

    uint4 twn[3];
#pragma unroll
    for (int ks = 0; ks < 3; ++ks) twn[ks] = tab[(w * 3 + ks) * 64 + lane];
    for (int mt = w; mt < 53; mt += 4) {
      uint4 twc[3];
#pragma unroll
      for (int ks = 0; ks < 3; ++ks) twc[ks] = twn[ks];
      int mtn = mt + 4;
      if (mtn < 53) {
#pragma unroll
        for (int ks = 0; ks < 3; ++ks) twn[ks] = tab[(mtn * 3 + ks) * 64 + lane];
      }
      f32x4 a2[2];
      mlp_core<3>(twc, lane, wf1r, wf2r, b1v, b2v, SM, hrow, a2);
      scatter_e<14, 840>(a2, mt * 16 + q4, ebf, cl);
    }
  }

  __syncthreads();  // ebar complete
  {
    short* ebb = (short*)(SM + EBB_B);
    for (int k = tid; k < 1200; k += 256) ebb[k] = f2bfs(ebf[k]);
  }
  __syncthreads();

  // ================= output MLP (4 tiles, one per wave) =================
  {
    const uint4* tab = (const uint4*)(wsb + TABO_B);
    u32x4 wf1r[12], wf2r[4];
    load_pin<12>(wf1r, wsb + WO1_B, lane);
    load_pin<4>(wf2r, wsb + WO2_B, lane);
    float b1v[4], b2v[2];
#pragma unroll
    for (int nt = 0; nt < 4; ++nt) b1v[nt] = biasf[192 + nt * 16 + cl];
#pragma unroll
    for (int nt = 0; nt < 2; ++nt) b2v[nt] = biasf[256 + nt * 16 + cl];

    uint4 twc[3];
#pragma unroll
    for (int ks = 0; ks < 3; ++ks) twc[ks] = tab[(w * 3 + ks) * 64 + lane];
    f32x4 a2[2];
    mlp_core<3>(twc, lane, wf1r, wf2r, b1v, b2v, SM, hrow, a2);

    int rb = w * 16 + q4;
#pragma unroll
    for (int nt = 0; nt < 2; ++nt) {
      int col = nt * 16 + cl;
      if (col < 24) {
        if (rb + 3 < 60) {
          atomicAdd(&osum[col], a2[nt][0] + a2[nt][1] + a2[nt][2] + a2[nt][3]);
        } else {
#pragma unroll
          for (int r = 0; r < 4; ++r)
            if (rb + r < 60) atomicAdd(&osum[col], a2[nt][r]);
        }
      }
    }
  }

  __syncthreads();
  if (tid == 0) {
    float sd = Bc[0];
#pragma unroll
    for (int o = 0; o < 24; ++o) sd = fmaf(osum[o], Wc[o], sd);
    out[b] = 1.f / (1.f + expf(-sd));
  }
}

extern "C" void kernel_launch(void* const* d_in, const int* in_sizes, int n_in,
                              void* d_out, int out_size, void* d_ws, size_t ws_size,
                              hipStream_t stream) {
  const float* x     = (const float*)d_in[0];
  const float* y     = (const float*)d_in[1];
  const float* W1_pp = (const float*)d_in[2];
  const float* b1_pp = (const float*)d_in[3];
  const float* W2_pp = (const float*)d_in[4];
  const float* b2_pp = (const float*)d_in[5];
  const float* W1_pv = (const float*)d_in[6];
  const float* b1_pv = (const float*)d_in[7];
  const float* W2_pv = (const float*)d_in[8];
  const float* b2_pv = (const float*)d_in[9];
  const float* W1_o  = (const float*)d_in[10];
  const float* b1_o  = (const float*)d_in[11];
  const float* W2_o  = (const float*)d_in[12];
  const float* b2_o  = (const float*)d_in[13];
  const float* Wc    = (const float*)d_in[14];
  const float* bc    = (const float*)d_in[15];
  float* out = (float*)d_out;
  char* wsb = (char*)d_ws;

  const int Bb = in_sizes[0] / 3600;  // 1024
  const int tab_total = NTAB_PP + NTAB_PV + NTAB_O;  // 542208

  build_tables<<<(tab_total + 255) / 256, 256, 0, stream>>>(wsb);
  build_wfrag<<<(13312 + 288 + 255) / 256, 256, 0, stream>>>(wsb,
      W1_pp, W2_pp, W1_pv, W2_pv, W1_o, W2_o,
      b1_pp, b2_pp, b1_pv, b2_pv, b1_o, b2_o);
  fused_kernel<<<Bb, 256, 0, stream>>>(x, y, Wc, bc, wsb, out);
}